// Round 3
// baseline (275.059 us; speedup 1.0000x reference)
//
#include <hip/hip_runtime.h>

// ---------------------------------------------------------------------------
// Matcher: 5-node star-graph GCN x 262144 instance graphs + 21 class graphs,
// then 105-dim similarity vs 21 classes.
//
// Key reduction: per-graph output sim[c] = A'[n0][c] + sum_{t=1..4} P_t[n0][n_t][c]
// where P_t is a (129 x 129 x 21) pair table and A' a (129 x 21) table.
// Precompute ~0.37 GFLOP of tables, then the main pass is a pure gather+add.
// ---------------------------------------------------------------------------

#define IS2 0.70710678118654752440f

constexpr int NE  = 129;   // embedding rows (node vocabulary)
constexpr int D1  = 128;   // hidden dim
constexpr int DF  = 21;    // feature dim == n classes
constexpr int NC  = 21;    // classes
constexpr int ROW = 24;    // padded row (21 -> 24 floats, 96B, 16B-aligned)

// workspace layout (float offsets; all 16B-aligned)
constexpr int U_OFF  = 0;                    // u[129][128]
constexpr int GT_OFF = U_OFF + NE * D1;      // Gt[128][84]   (84 = 4t x 21c, 0.5 folded)
constexpr int A_OFF  = GT_OFF + D1 * 84;     // A'[129][24]
constexpr int P_OFF  = A_OFF + NE * ROW;     // P[4][129][129][24]

constexpr int BT  = 16;                      // b-tile in pair kernel
constexpr int NBT = (NE + BT - 1) / BT;      // 9

// ---------------------------------------------------------------------------
// K1: u[i][j] = sum_k emb[i][k] * W1[k][j]    (129 x 128, trivial)
// ---------------------------------------------------------------------------
__global__ __launch_bounds__(D1) void k_u(const float* __restrict__ emb,
                                          const float* __restrict__ W1,
                                          float* __restrict__ u) {
    int i = blockIdx.x;       // 0..128
    int j = threadIdx.x;      // 0..127
    __shared__ float e[DF];
    if (threadIdx.x < DF) e[threadIdx.x] = emb[i * DF + threadIdx.x];
    __syncthreads();
    float acc = 0.f;
#pragma unroll
    for (int k = 0; k < DF; ++k) acc += e[k] * W1[k * D1 + j];
    u[i * D1 + j] = acc;
}

// ---------------------------------------------------------------------------
// K2: class branch (21 tiny GCNs) -> out_class, then Gt[128][84], A'[129][24].
// Single block of 256 threads; total ~1.2M MACs (~4-5 us on one CU).
// ---------------------------------------------------------------------------
__global__ __launch_bounds__(256) void k_class(const int* __restrict__ cn,
                                               const float* __restrict__ b1,
                                               const float* __restrict__ W2,
                                               const float* __restrict__ b2,
                                               float* __restrict__ ws) {
    const float* u  = ws + U_OFF;
    float* gGt = ws + GT_OFF;
    float* gA  = ws + A_OFF;

    // smem regions:
    //  phase1: h  at [0 .. 13440)   (21 graphs x 5 nodes x 128)
    //          v  at [13440 .. 15645)  (21 x 5 x 21)
    //  phase2 (h dead): oc at [0..2205), S at [2205..2646),
    //                   G0p at [2646..5334), cst at [5334..5355)
    __shared__ float sm[15648];
    const int tid = threadIdx.x;

    // h[c][s][k]
    for (int e = tid; e < NC * 5 * D1; e += 256) {
        int c = e / (5 * D1); int r = e % (5 * D1); int s = r / D1; int k = r % D1;
        int n0 = cn[c * 5];
        float pre;
        if (s == 0) {
            pre = u[n0 * D1 + k] + b1[k];
        } else {
            int ns = cn[c * 5 + s];
            pre = IS2 * u[n0 * D1 + k] + 0.5f * u[ns * D1 + k] + b1[k];
        }
        sm[e] = fmaxf(pre, 0.f);
    }
    __syncthreads();

    // v[c][s][j] = h[c][s] @ W2
    for (int e = tid; e < NC * 5 * DF; e += 256) {
        int c = e / (5 * DF); int r = e % (5 * DF); int s = r / DF; int j = r % DF;
        const float* h = sm + (c * 5 + s) * D1;
        float a0 = 0.f, a1 = 0.f;
#pragma unroll 8
        for (int k = 0; k < D1; k += 2) {
            a0 += h[k]     * W2[k * DF + j];
            a1 += h[k + 1] * W2[(k + 1) * DF + j];
        }
        sm[13440 + e] = a0 + a1;
    }
    __syncthreads();

    // oc[c][t*21+j]  (overwrites dead h region)
    for (int e = tid; e < NC * 105; e += 256) {
        int c = e / 105; int r = e % 105; int t = r / DF; int j = r % DF;
        float v0 = sm[13440 + (c * 5 + 0) * DF + j];
        float val;
        if (t == 0) val = v0 + b2[j];
        else        val = IS2 * v0 + 0.5f * sm[13440 + (c * 5 + t) * DF + j] + b2[j];
        sm[e] = val;
    }
    __syncthreads();

    // S[c][j] = sum_{t=1..4} oc[c][t*21+j]
    for (int e = tid; e < NC * DF; e += 256) {
        int c = e / DF, j = e % DF;
        sm[2205 + e] = sm[c * 105 + 21 + j] + sm[c * 105 + 42 + j]
                     + sm[c * 105 + 63 + j] + sm[c * 105 + 84 + j];
    }
    __syncthreads();

    // Gt[k][tc] = 0.5 * sum_j W2[k][j] * oc[c][ (t+1)*21 + j ]   (global, transposed)
    for (int e = tid; e < D1 * 84; e += 256) {
        int k = e / 84, tc = e % 84; int t = tc / DF + 1, c = tc % DF;
        float acc = 0.f;
#pragma unroll
        for (int j = 0; j < DF; ++j) acc += W2[k * DF + j] * sm[c * 105 + t * DF + j];
        gGt[e] = 0.5f * acc;
    }
    // G0p[c][k] = sum_j W2[k][j] * (oc[c][j] + is2 * S[c][j])   (smem, no barrier
    // needed: writes [2646..5334) never read by concurrent loops above)
    for (int e = tid; e < NC * D1; e += 256) {
        int c = e / D1, k = e % D1;
        float acc = 0.f;
#pragma unroll
        for (int j = 0; j < DF; ++j)
            acc += W2[k * DF + j] * (sm[c * 105 + j] + IS2 * sm[2205 + c * DF + j]);
        sm[2646 + e] = acc;
    }
    // cst[c] = dot(b2, C0[c] + S[c])
    for (int e = tid; e < NC; e += 256) {
        float acc = 0.f;
#pragma unroll
        for (int j = 0; j < DF; ++j) acc += b2[j] * (sm[e * 105 + j] + sm[2205 + e * DF + j]);
        sm[5334 + e] = acc;
    }
    __syncthreads();

    // A'[n0][c] = cst[c] + dot(relu(u[n0]+b1), G0p[c])
    for (int e = tid; e < NE * NC; e += 256) {
        int n0 = e / NC, c = e % NC;
        const float* un = u + n0 * D1;
        const float* g  = sm + 2646 + c * D1;
        float a0 = 0.f, a1 = 0.f;
#pragma unroll 8
        for (int k = 0; k < D1; k += 2) {
            a0 += fmaxf(un[k]     + b1[k],     0.f) * g[k];
            a1 += fmaxf(un[k + 1] + b1[k + 1], 0.f) * g[k + 1];
        }
        gA[n0 * ROW + c] = sm[5334 + c] + a0 + a1;
    }
}

// ---------------------------------------------------------------------------
// K3: pair tables P[t][a][b][c] = dot(relu(is2*u[a] + 0.5*u[b] + b1), Gt[:,tc])
// Grid: 129 * 9 blocks, 256 threads. Gt reads are [k][tc]-major -> coalesced
// and shared across the whole grid (43KB, L1/L2 resident). Two-accumulator
// split halves the serial FMA dependency chain (latency-bound otherwise).
// ---------------------------------------------------------------------------
__global__ __launch_bounds__(256) void k_pair(const float* __restrict__ b1,
                                              float* __restrict__ ws) {
    const float* u   = ws + U_OFF;
    const float* gGt = ws + GT_OFF;
    float* P         = ws + P_OFF;

    int a  = blockIdx.x / NBT;
    int b0 = (blockIdx.x % NBT) * BT;

    __shared__ float ua[D1];        // is2*u[a] + b1 folded
    __shared__ float hp[BT * D1];
    const int tid = threadIdx.x;

    if (tid < D1) ua[tid] = IS2 * u[a * D1 + tid] + b1[tid];
    __syncthreads();

    for (int e = tid; e < BT * D1; e += 256) {
        int p = e / D1, k = e % D1; int b = b0 + p;
        float val = 0.f;
        if (b < NE) val = fmaxf(ua[k] + 0.5f * u[b * D1 + k], 0.f);
        hp[e] = val;
    }
    __syncthreads();

    for (int o = tid; o < BT * 84; o += 256) {
        int p = o / 84, tc = o % 84; int b = b0 + p;
        if (b >= NE) continue;
        const float* h = hp + p * D1;
        float a0 = 0.f, a1 = 0.f;
#pragma unroll 8
        for (int k = 0; k < D1; k += 2) {
            a0 += h[k]     * gGt[k * 84 + tc];
            a1 += h[k + 1] * gGt[(k + 1) * 84 + tc];
        }
        int t = tc / DF, c = tc % DF;   // t: 0..3 meaning graph slot t+1
        P[((long long)t * NE * NE + (long long)a * NE + b) * ROW + c] = a0 + a1;
    }
}

// ---------------------------------------------------------------------------
// K4: main pass. One thread per graph. Indices staged through LDS with
// coalesced int4 loads; 5 gathered float4x6 table rows; LDS-staged coalesced
// 21-float output write.
// ---------------------------------------------------------------------------
__global__ __launch_bounds__(256) void k_main(const int* __restrict__ inst,
                                              const float* __restrict__ ws,
                                              float* __restrict__ out,
                                              long long n_graphs) {
    const float* gA = ws + A_OFF;
    const float* P  = ws + P_OFF;

    __shared__ float so[256 * NC];          // 21.5 KB
    __shared__ int   si[256 * 5];           // 5 KB
    const int tid = threadIdx.x;
    const long long gbase = (long long)blockIdx.x * 256;
    const bool full = (gbase + 256 <= n_graphs);

    // coalesced index stage: 1280 ints = 320 int4 (tail block: scalar guarded)
    if (full) {
        const int4* src = (const int4*)(inst + gbase * 5);
        int4* dst = (int4*)si;
        for (int i = tid; i < 320; i += 256) dst[i] = src[i];
    } else {
        long long lim = (n_graphs - gbase) * 5;
        for (int i = tid; i < 256 * 5; i += 256)
            si[i] = (i < lim) ? inst[gbase * 5 + i] : 0;
    }
    __syncthreads();

    const long long g = gbase + tid;
    if (g < n_graphs) {
        const int n0 = si[tid * 5 + 0];
        const int n1 = si[tid * 5 + 1];
        const int n2 = si[tid * 5 + 2];
        const int n3 = si[tid * 5 + 3];
        const int n4 = si[tid * 5 + 4];

        const float4* pa = (const float4*)(gA + (long long)n0 * ROW);
        const float4* p1 = (const float4*)(P + ((long long)0 * NE * NE + (long long)n0 * NE + n1) * ROW);
        const float4* p2 = (const float4*)(P + ((long long)1 * NE * NE + (long long)n0 * NE + n2) * ROW);
        const float4* p3 = (const float4*)(P + ((long long)2 * NE * NE + (long long)n0 * NE + n3) * ROW);
        const float4* p4 = (const float4*)(P + ((long long)3 * NE * NE + (long long)n0 * NE + n4) * ROW);

        float acc[ROW];
#pragma unroll
        for (int q = 0; q < ROW / 4; ++q) {
            float4 a0 = pa[q], a1 = p1[q], a2 = p2[q], a3 = p3[q], a4 = p4[q];
            acc[4 * q + 0] = a0.x + a1.x + a2.x + a3.x + a4.x;
            acc[4 * q + 1] = a0.y + a1.y + a2.y + a3.y + a4.y;
            acc[4 * q + 2] = a0.z + a1.z + a2.z + a3.z + a4.z;
            acc[4 * q + 3] = a0.w + a1.w + a2.w + a3.w + a4.w;
        }

#pragma unroll
        for (int c = 0; c < NC; ++c) so[tid * NC + c] = acc[c];  // pads discarded
    }
    __syncthreads();

    const long long lim = (n_graphs - gbase) * NC;
    const long long base = gbase * NC;
    for (int i = tid; i < 256 * NC; i += 256)
        if (i < lim) out[base + i] = so[i];
}

// ---------------------------------------------------------------------------
extern "C" void kernel_launch(void* const* d_in, const int* in_sizes, int n_in,
                              void* d_out, int out_size, void* d_ws, size_t ws_size,
                              hipStream_t stream) {
    const int*   inst = (const int*)d_in[0];    // [4,256,256,5]
    const int*   cn   = (const int*)d_in[1];    // [21,5]
    const float* emb  = (const float*)d_in[2];  // [129,21]
    const float* W1   = (const float*)d_in[3];  // [21,128]
    const float* b1   = (const float*)d_in[4];  // [128]
    const float* W2   = (const float*)d_in[5];  // [128,21]
    const float* b2   = (const float*)d_in[6];  // [21]
    float* out = (float*)d_out;
    float* ws  = (float*)d_ws;   // needs ~6.6 MB

    const long long n_graphs = (long long)in_sizes[0] / 5;   // 262144
    const int nblk = (int)((n_graphs + 255) / 256);

    k_u    <<<dim3(NE), dim3(D1), 0, stream>>>(emb, W1, ws + U_OFF);
    k_class<<<dim3(1), dim3(256), 0, stream>>>(cn, b1, W2, b2, ws);
    k_pair <<<dim3(NE * NBT), dim3(256), 0, stream>>>(b1, ws);
    k_main <<<dim3(nblk), dim3(256), 0, stream>>>(inst, ws, out, n_graphs);
}

// Round 10
// 143.992 us; speedup vs baseline: 1.9102x; 1.9102x over previous
//
#include <hip/hip_runtime.h>

// ---------------------------------------------------------------------------
// Matcher: 5-node star-graph GCN x 262144 instance graphs + 21 class graphs,
// then 105-dim similarity vs 21 classes.
//
// sim[c] = cst[c] + dot(relu(u[n0]+b1), G0p[c]) + sum_{t=1..4} P_t[n0][n_t][c]
// with P_t[a][b][c] = dot(relu(is2*u[a]+0.5*u[b]+b1), Gt[:,(t-1)*21+c]).
// Precompute ~0.37 GFLOP of tables, then the main pass is a pure gather+add.
//
// R3: split the single-block k_class (133us, occupancy 0.045%) into 3
//     parallel kernels; rowP runtime-selected 32 (one aligned 128B line per
//     gather row) when ws_size permits, else 24.
// R4: k_pair was LDS/L1-BW-bound (~4B/FLOP): stage Gt (43KB) in LDS and
//     register-tile 2p x 3tc outputs/thread -> 2.4x less LDS traffic.
// R5-R9: resubmit (GPU acquisition timeouts; R3/R4 changes still unbenched).
// ---------------------------------------------------------------------------

#define IS2 0.70710678118654752440f

constexpr int NE  = 129;   // embedding rows (node vocabulary)
constexpr int D1  = 128;   // hidden dim
constexpr int DF  = 21;    // feature dim == n classes
constexpr int NC  = 21;    // classes
constexpr int ROWA = 24;   // A' row pad (96B, 16B-aligned)

// workspace layout (float offsets; static regions before P)
constexpr int U_OFF   = 0;                      // u[129][128]
constexpr int GT_OFF  = U_OFF  + NE * D1;       // Gt[128][84]  (0.5 folded)
constexpr int A_OFF   = GT_OFF + D1 * 84;       // A'[129][24]
constexpr int OC_OFF  = A_OFF  + NE * ROWA;     // oc[21][105]
constexpr int S_OFF   = OC_OFF + NC * 105;      // S[21][21]
constexpr int G0_OFF  = S_OFF  + NC * DF;       // G0p[21][128]
constexpr int CST_OFF = G0_OFF + NC * D1;       // cst[21]
constexpr int P_OFF   = ((CST_OFF + NC + 31) / 32) * 32;  // 128B-aligned
constexpr long long P_ELEMS32 = 4LL * NE * NE * 32;

constexpr int BT  = 16;                         // b-tile in pair kernel
constexpr int NBT = (NE + BT - 1) / BT;         // 9

// ---------------------------------------------------------------------------
// K1: u[i][j] = sum_k emb[i][k] * W1[k][j]    (129 x 128, trivial)
// ---------------------------------------------------------------------------
__global__ __launch_bounds__(D1) void k_u(const float* __restrict__ emb,
                                          const float* __restrict__ W1,
                                          float* __restrict__ u) {
    int i = blockIdx.x;       // 0..128
    int j = threadIdx.x;      // 0..127
    __shared__ float e[DF];
    if (threadIdx.x < DF) e[threadIdx.x] = emb[i * DF + threadIdx.x];
    __syncthreads();
    float acc = 0.f;
#pragma unroll
    for (int k = 0; k < DF; ++k) acc += e[k] * W1[k * D1 + j];
    u[i * D1 + j] = acc;
}

// ---------------------------------------------------------------------------
// K2a: per-class tiny GCN -> oc[c][105], S[c][21], cst[c].  21 blocks x 128.
// ---------------------------------------------------------------------------
__global__ __launch_bounds__(D1) void k_class_a(const int* __restrict__ cn,
                                                const float* __restrict__ b1,
                                                const float* __restrict__ W2,
                                                const float* __restrict__ b2,
                                                float* __restrict__ ws) {
    const float* u = ws + U_OFF;
    float* oc  = ws + OC_OFF;
    float* S   = ws + S_OFF;
    float* cst = ws + CST_OFF;

    const int c   = blockIdx.x;
    const int tid = threadIdx.x;

    __shared__ float h[5 * D1];
    __shared__ float v[5 * DF];
    __shared__ float ocs[105];
    __shared__ float Ss[DF];

    const int n0 = cn[c * 5];
#pragma unroll
    for (int s = 0; s < 5; ++s) {
        int ns = cn[c * 5 + s];
        float pre = (s == 0) ? (u[n0 * D1 + tid] + b1[tid])
                             : (IS2 * u[n0 * D1 + tid] + 0.5f * u[ns * D1 + tid] + b1[tid]);
        h[s * D1 + tid] = fmaxf(pre, 0.f);
    }
    __syncthreads();

    if (tid < 105) {
        int s = tid / DF, j = tid % DF;
        const float* hs = h + s * D1;
        float a0 = 0.f, a1 = 0.f;
#pragma unroll 8
        for (int k = 0; k < D1; k += 2) {
            a0 += hs[k]     * W2[k * DF + j];
            a1 += hs[k + 1] * W2[(k + 1) * DF + j];
        }
        v[tid] = a0 + a1;
    }
    __syncthreads();

    if (tid < 105) {
        int t = tid / DF, j = tid % DF;
        float v0 = v[j];
        float val = (t == 0) ? (v0 + b2[j])
                             : (IS2 * v0 + 0.5f * v[t * DF + j] + b2[j]);
        ocs[tid] = val;
        oc[c * 105 + tid] = val;
    }
    __syncthreads();

    if (tid < DF) {
        float sv = ocs[21 + tid] + ocs[42 + tid] + ocs[63 + tid] + ocs[84 + tid];
        Ss[tid] = sv;
        S[c * DF + tid] = sv;
    }
    __syncthreads();

    if (tid == 0) {
        float acc = 0.f;
#pragma unroll
        for (int j = 0; j < DF; ++j) acc += b2[j] * (ocs[j] + Ss[j]);
        cst[c] = acc;
    }
}

// ---------------------------------------------------------------------------
// K2b: Gt[k][tc] and G0p[c][k].  13440 outputs x 21 MACs.  53 blocks x 256.
// ---------------------------------------------------------------------------
__global__ __launch_bounds__(256) void k_class_b(const float* __restrict__ W2,
                                                 float* __restrict__ ws) {
    const float* oc = ws + OC_OFF;
    const float* S  = ws + S_OFF;
    float* gGt = ws + GT_OFF;
    float* G0  = ws + G0_OFF;

    int idx = blockIdx.x * 256 + threadIdx.x;
    if (idx < D1 * 84) {
        int k = idx / 84, tc = idx % 84;
        int t = tc / DF + 1, c = tc % DF;
        float acc = 0.f;
#pragma unroll
        for (int j = 0; j < DF; ++j) acc += W2[k * DF + j] * oc[c * 105 + t * DF + j];
        gGt[idx] = 0.5f * acc;
    } else if (idx < D1 * 84 + NC * D1) {
        int r = idx - D1 * 84;
        int c = r / D1, k = r % D1;
        float acc = 0.f;
#pragma unroll
        for (int j = 0; j < DF; ++j)
            acc += W2[k * DF + j] * (oc[c * 105 + j] + IS2 * S[c * DF + j]);
        G0[c * D1 + k] = acc;
    }
}

// ---------------------------------------------------------------------------
// K2c: A'[n0][c] = cst[c] + dot(relu(u[n0]+b1), G0p[c]).  129 blocks x 128.
// ---------------------------------------------------------------------------
__global__ __launch_bounds__(D1) void k_class_c(const float* __restrict__ b1,
                                                float* __restrict__ ws) {
    const float* u   = ws + U_OFF;
    const float* G0  = ws + G0_OFF;
    const float* cst = ws + CST_OFF;
    float* gA = ws + A_OFF;

    const int n0  = blockIdx.x;
    const int tid = threadIdx.x;

    __shared__ float h0[D1];
    h0[tid] = fmaxf(u[n0 * D1 + tid] + b1[tid], 0.f);
    __syncthreads();

    if (tid < NC) {
        const float* g = G0 + tid * D1;
        float a0 = 0.f, a1 = 0.f;
#pragma unroll 8
        for (int k = 0; k < D1; k += 2) {
            a0 += h0[k]     * g[k];
            a1 += h0[k + 1] * g[k + 1];
        }
        gA[n0 * ROWA + tid] = cst[tid] + a0 + a1;
    }
}

// ---------------------------------------------------------------------------
// K3: pair tables P[t][a][b][c] = dot(relu(is2*u[a] + 0.5*u[b] + b1), Gt[:,tc])
// Grid: 129 * 9 blocks, 256 threads. Gt staged in LDS (43KB); each thread
// computes a 2p x 3tc register tile (640 LDS reads per 768 FMAs, was 1536).
// Even/odd-k accumulator split keeps the serial FMA chain short and the
// summation order identical to the untiled version.
// ---------------------------------------------------------------------------
__global__ __launch_bounds__(256) void k_pair(const float* __restrict__ b1,
                                              float* __restrict__ ws, int rowP) {
    const float* u   = ws + U_OFF;
    const float* gGt = ws + GT_OFF;
    float* P         = ws + P_OFF;

    const int a  = blockIdx.x / NBT;
    const int b0 = (blockIdx.x % NBT) * BT;

    __shared__ float ua[D1];          // is2*u[a] + b1 folded
    __shared__ float hp[BT * D1];     // relu'd pair hidden, 8KB
    __shared__ float gt[D1 * 84];     // Gt staged, 43KB
    const int tid = threadIdx.x;

    if (tid < D1) ua[tid] = IS2 * u[a * D1 + tid] + b1[tid];
    // coalesced Gt stage: 10752 floats = 2688 float4
    {
        const float4* src = (const float4*)gGt;
        float4* dst = (float4*)gt;
        for (int i = tid; i < D1 * 84 / 4; i += 256) dst[i] = src[i];
    }
    __syncthreads();

    for (int e = tid; e < BT * D1; e += 256) {
        int p = e / D1, k = e % D1; int b = b0 + p;
        float val = 0.f;
        if (b < NE) val = fmaxf(ua[k] + 0.5f * u[b * D1 + k], 0.f);
        hp[e] = val;
    }
    __syncthreads();

    // 2p x 3tc tiles: 8 * 28 = 224 tiles; threads 224..255 idle.
    if (tid < (BT / 2) * 28) {
        const int p0  = (tid / 28) * 2;
        const int tc0 = (tid % 28) * 3;       // 3 | 21 -> tile within one t
        const float* hA = hp + p0 * D1;
        const float* hB = hA + D1;

        float e00 = 0.f, e01 = 0.f, e02 = 0.f, e10 = 0.f, e11 = 0.f, e12 = 0.f;
        float o00 = 0.f, o01 = 0.f, o02 = 0.f, o10 = 0.f, o11 = 0.f, o12 = 0.f;
#pragma unroll 4
        for (int k = 0; k < D1; k += 2) {
            float ha0 = hA[k], hb0 = hB[k];
            float ha1 = hA[k + 1], hb1 = hB[k + 1];
            const float* g0 = gt + k * 84 + tc0;
            const float* g1 = g0 + 84;
            float ge0 = g0[0], ge1 = g0[1], ge2 = g0[2];
            float go0 = g1[0], go1 = g1[1], go2 = g1[2];
            e00 += ha0 * ge0; e01 += ha0 * ge1; e02 += ha0 * ge2;
            e10 += hb0 * ge0; e11 += hb0 * ge1; e12 += hb0 * ge2;
            o00 += ha1 * go0; o01 += ha1 * go1; o02 += ha1 * go2;
            o10 += hb1 * go0; o11 += hb1 * go1; o12 += hb1 * go2;
        }

        const int t  = tc0 / DF;
        const int c0 = tc0 - t * DF;
        const long long rbase = (long long)(t * NE * NE + a * NE);
        const int bA = b0 + p0, bB = bA + 1;
        if (bA < NE) {
            float* dst = P + (rbase + bA) * rowP + c0;
            dst[0] = e00 + o00; dst[1] = e01 + o01; dst[2] = e02 + o02;
        }
        if (bB < NE) {
            float* dst = P + (rbase + bB) * rowP + c0;
            dst[0] = e10 + o10; dst[1] = e11 + o11; dst[2] = e12 + o12;
        }
    }
}

// ---------------------------------------------------------------------------
// K4: main pass. One thread per graph. Indices staged through LDS with
// coalesced int4 loads; 5 gathered table rows; LDS-staged coalesced write.
// ---------------------------------------------------------------------------
__global__ __launch_bounds__(256) void k_main(const int* __restrict__ inst,
                                              const float* __restrict__ ws,
                                              float* __restrict__ out,
                                              long long n_graphs, int rowP) {
    const float* gA = ws + A_OFF;
    const float* P  = ws + P_OFF;

    __shared__ float so[256 * NC];          // 21.5 KB
    __shared__ int   si[256 * 5];           // 5 KB
    const int tid = threadIdx.x;
    const long long gbase = (long long)blockIdx.x * 256;
    const bool full = (gbase + 256 <= n_graphs);

    // coalesced index stage: 1280 ints = 320 int4 (tail block: scalar guarded)
    if (full) {
        const int4* src = (const int4*)(inst + gbase * 5);
        int4* dst = (int4*)si;
        for (int i = tid; i < 320; i += 256) dst[i] = src[i];
    } else {
        long long lim = (n_graphs - gbase) * 5;
        for (int i = tid; i < 256 * 5; i += 256)
            si[i] = (i < lim) ? inst[gbase * 5 + i] : 0;
    }
    __syncthreads();

    const long long g = gbase + tid;
    if (g < n_graphs) {
        const int n0 = si[tid * 5 + 0];
        const int n1 = si[tid * 5 + 1];
        const int n2 = si[tid * 5 + 2];
        const int n3 = si[tid * 5 + 3];
        const int n4 = si[tid * 5 + 4];

        const int nn = NE * NE;
        const float4* pa = (const float4*)(gA + n0 * ROWA);
        const float4* p1 = (const float4*)(P + (long long)((0 * nn + n0 * NE + n1)) * rowP);
        const float4* p2 = (const float4*)(P + (long long)((1 * nn + n0 * NE + n2)) * rowP);
        const float4* p3 = (const float4*)(P + (long long)((2 * nn + n0 * NE + n3)) * rowP);
        const float4* p4 = (const float4*)(P + (long long)((3 * nn + n0 * NE + n4)) * rowP);

        float acc[ROWA];
#pragma unroll
        for (int q = 0; q < ROWA / 4; ++q) {
            float4 a0 = pa[q], a1 = p1[q], a2 = p2[q], a3 = p3[q], a4 = p4[q];
            acc[4 * q + 0] = a0.x + a1.x + a2.x + a3.x + a4.x;
            acc[4 * q + 1] = a0.y + a1.y + a2.y + a3.y + a4.y;
            acc[4 * q + 2] = a0.z + a1.z + a2.z + a3.z + a4.z;
            acc[4 * q + 3] = a0.w + a1.w + a2.w + a3.w + a4.w;
        }

#pragma unroll
        for (int c = 0; c < NC; ++c) so[tid * NC + c] = acc[c];  // pads discarded
    }
    __syncthreads();

    const long long lim = (n_graphs - gbase) * NC;
    const long long base = gbase * NC;
    for (int i = tid; i < 256 * NC; i += 256)
        if (i < lim) out[base + i] = so[i];
}

// ---------------------------------------------------------------------------
extern "C" void kernel_launch(void* const* d_in, const int* in_sizes, int n_in,
                              void* d_out, int out_size, void* d_ws, size_t ws_size,
                              hipStream_t stream) {
    const int*   inst = (const int*)d_in[0];    // [4,256,256,5]
    const int*   cn   = (const int*)d_in[1];    // [21,5]
    const float* emb  = (const float*)d_in[2];  // [129,21]
    const float* W1   = (const float*)d_in[3];  // [21,128]
    const float* b1   = (const float*)d_in[4];  // [128]
    const float* W2   = (const float*)d_in[5];  // [128,21]
    const float* b2   = (const float*)d_in[6];  // [21]
    float* out = (float*)d_out;
    float* ws  = (float*)d_ws;

    const long long n_graphs = (long long)in_sizes[0] / 5;   // 262144
    const int nblk = (int)((n_graphs + 255) / 256);

    // one 128B-aligned cache line per pair-row if workspace permits (8.8MB)
    const int rowP =
        (ws_size >= (size_t)(P_OFF + P_ELEMS32) * sizeof(float)) ? 32 : 24;

    k_u      <<<dim3(NE),       dim3(D1),  0, stream>>>(emb, W1, ws + U_OFF);
    k_class_a<<<dim3(NC),       dim3(D1),  0, stream>>>(cn, b1, W2, b2, ws);
    k_class_b<<<dim3(53),       dim3(256), 0, stream>>>(W2, ws);
    k_class_c<<<dim3(NE),       dim3(D1),  0, stream>>>(b1, ws);
    k_pair   <<<dim3(NE * NBT), dim3(256), 0, stream>>>(b1, ws, rowP);
    k_main   <<<dim3(nblk),     dim3(256), 0, stream>>>(inst, ws, out, n_graphs, rowP);
}

// Round 12
// 127.369 us; speedup vs baseline: 2.1595x; 1.1305x over previous
//
#include <hip/hip_runtime.h>

// ---------------------------------------------------------------------------
// Matcher: 5-node star-graph GCN x 262144 instance graphs + 21 class graphs,
// then 105-dim similarity vs 21 classes.
//
// sim[c] = cst[c] + dot(relu(u[n0]+b1), G0p[c]) + sum_{t=1..4} P_t[n0][n_t][c]
// with P_t[a][b][c] = dot(relu(is2*u[a]+0.5*u[b]+b1), Gt[:,(t-1)*21+c]).
// Precompute ~0.37 GFLOP of tables, then the main pass is a pure gather+add.
//
// R3:  split single-block k_class (133us, occ 0.045%) into 3 parallel kernels.
//      MEASURED R10: 275 -> 144us, matches k_class removal.
// R4:  k_pair LDS-staged Gt + 2px3tc register tile.
// R10: k_main was ~120us (reconstructed): 30 concurrent float4 gathers/thread
//      = 40KB of distinct lines in flight > 32KB L1 -> each 128B row-line
//      fetched up to 6x (once per float4 touch) -> ~1GB L2/LLC traffic.
//      Fix: 6 threads per graph, lane q reads chunk q of all 5 rows; a row's
//      line is consumed by its 6 lanes in the SAME instruction -> each line
//      fetched once, 168MB total. Predicted k_main ~15-20us, total ~35-55us.
// R11: resubmit (GPU acquisition timeout; R10 k_main fix unbenched).
// ---------------------------------------------------------------------------

#define IS2 0.70710678118654752440f

constexpr int NE  = 129;   // embedding rows (node vocabulary)
constexpr int D1  = 128;   // hidden dim
constexpr int DF  = 21;    // feature dim == n classes
constexpr int NC  = 21;    // classes
constexpr int ROWA = 24;   // A' row pad (96B, 16B-aligned)

// workspace layout (float offsets; static regions before P)
constexpr int U_OFF   = 0;                      // u[129][128]
constexpr int GT_OFF  = U_OFF  + NE * D1;       // Gt[128][84]  (0.5 folded)
constexpr int A_OFF   = GT_OFF + D1 * 84;       // A'[129][24]
constexpr int OC_OFF  = A_OFF  + NE * ROWA;     // oc[21][105]
constexpr int S_OFF   = OC_OFF + NC * 105;      // S[21][21]
constexpr int G0_OFF  = S_OFF  + NC * DF;       // G0p[21][128]
constexpr int CST_OFF = G0_OFF + NC * D1;       // cst[21]
constexpr int P_OFF   = ((CST_OFF + NC + 31) / 32) * 32;  // 128B-aligned
constexpr long long P_ELEMS32 = 4LL * NE * NE * 32;

constexpr int BT  = 16;                         // b-tile in pair kernel
constexpr int NBT = (NE + BT - 1) / BT;         // 9

constexpr int GPB = 32;                         // graphs per k_main block
constexpr int TPG = 6;                          // threads per graph (chunk q)

// ---------------------------------------------------------------------------
// K1: u[i][j] = sum_k emb[i][k] * W1[k][j]    (129 x 128, trivial)
// ---------------------------------------------------------------------------
__global__ __launch_bounds__(D1) void k_u(const float* __restrict__ emb,
                                          const float* __restrict__ W1,
                                          float* __restrict__ u) {
    int i = blockIdx.x;       // 0..128
    int j = threadIdx.x;      // 0..127
    __shared__ float e[DF];
    if (threadIdx.x < DF) e[threadIdx.x] = emb[i * DF + threadIdx.x];
    __syncthreads();
    float acc = 0.f;
#pragma unroll
    for (int k = 0; k < DF; ++k) acc += e[k] * W1[k * D1 + j];
    u[i * D1 + j] = acc;
}

// ---------------------------------------------------------------------------
// K2a: per-class tiny GCN -> oc[c][105], S[c][21], cst[c].  21 blocks x 128.
// ---------------------------------------------------------------------------
__global__ __launch_bounds__(D1) void k_class_a(const int* __restrict__ cn,
                                                const float* __restrict__ b1,
                                                const float* __restrict__ W2,
                                                const float* __restrict__ b2,
                                                float* __restrict__ ws) {
    const float* u = ws + U_OFF;
    float* oc  = ws + OC_OFF;
    float* S   = ws + S_OFF;
    float* cst = ws + CST_OFF;

    const int c   = blockIdx.x;
    const int tid = threadIdx.x;

    __shared__ float h[5 * D1];
    __shared__ float v[5 * DF];
    __shared__ float ocs[105];
    __shared__ float Ss[DF];

    const int n0 = cn[c * 5];
#pragma unroll
    for (int s = 0; s < 5; ++s) {
        int ns = cn[c * 5 + s];
        float pre = (s == 0) ? (u[n0 * D1 + tid] + b1[tid])
                             : (IS2 * u[n0 * D1 + tid] + 0.5f * u[ns * D1 + tid] + b1[tid]);
        h[s * D1 + tid] = fmaxf(pre, 0.f);
    }
    __syncthreads();

    if (tid < 105) {
        int s = tid / DF, j = tid % DF;
        const float* hs = h + s * D1;
        float a0 = 0.f, a1 = 0.f;
#pragma unroll 8
        for (int k = 0; k < D1; k += 2) {
            a0 += hs[k]     * W2[k * DF + j];
            a1 += hs[k + 1] * W2[(k + 1) * DF + j];
        }
        v[tid] = a0 + a1;
    }
    __syncthreads();

    if (tid < 105) {
        int t = tid / DF, j = tid % DF;
        float v0 = v[j];
        float val = (t == 0) ? (v0 + b2[j])
                             : (IS2 * v0 + 0.5f * v[t * DF + j] + b2[j]);
        ocs[tid] = val;
        oc[c * 105 + tid] = val;
    }
    __syncthreads();

    if (tid < DF) {
        float sv = ocs[21 + tid] + ocs[42 + tid] + ocs[63 + tid] + ocs[84 + tid];
        Ss[tid] = sv;
        S[c * DF + tid] = sv;
    }
    __syncthreads();

    if (tid == 0) {
        float acc = 0.f;
#pragma unroll
        for (int j = 0; j < DF; ++j) acc += b2[j] * (ocs[j] + Ss[j]);
        cst[c] = acc;
    }
}

// ---------------------------------------------------------------------------
// K2b: Gt[k][tc] and G0p[c][k].  13440 outputs x 21 MACs.  53 blocks x 256.
// ---------------------------------------------------------------------------
__global__ __launch_bounds__(256) void k_class_b(const float* __restrict__ W2,
                                                 float* __restrict__ ws) {
    const float* oc = ws + OC_OFF;
    const float* S  = ws + S_OFF;
    float* gGt = ws + GT_OFF;
    float* G0  = ws + G0_OFF;

    int idx = blockIdx.x * 256 + threadIdx.x;
    if (idx < D1 * 84) {
        int k = idx / 84, tc = idx % 84;
        int t = tc / DF + 1, c = tc % DF;
        float acc = 0.f;
#pragma unroll
        for (int j = 0; j < DF; ++j) acc += W2[k * DF + j] * oc[c * 105 + t * DF + j];
        gGt[idx] = 0.5f * acc;
    } else if (idx < D1 * 84 + NC * D1) {
        int r = idx - D1 * 84;
        int c = r / D1, k = r % D1;
        float acc = 0.f;
#pragma unroll
        for (int j = 0; j < DF; ++j)
            acc += W2[k * DF + j] * (oc[c * 105 + j] + IS2 * S[c * DF + j]);
        G0[c * D1 + k] = acc;
    }
}

// ---------------------------------------------------------------------------
// K2c: A'[n0][c] = cst[c] + dot(relu(u[n0]+b1), G0p[c]).  129 blocks x 128.
// ---------------------------------------------------------------------------
__global__ __launch_bounds__(D1) void k_class_c(const float* __restrict__ b1,
                                                float* __restrict__ ws) {
    const float* u   = ws + U_OFF;
    const float* G0  = ws + G0_OFF;
    const float* cst = ws + CST_OFF;
    float* gA = ws + A_OFF;

    const int n0  = blockIdx.x;
    const int tid = threadIdx.x;

    __shared__ float h0[D1];
    h0[tid] = fmaxf(u[n0 * D1 + tid] + b1[tid], 0.f);
    __syncthreads();

    if (tid < NC) {
        const float* g = G0 + tid * D1;
        float a0 = 0.f, a1 = 0.f;
#pragma unroll 8
        for (int k = 0; k < D1; k += 2) {
            a0 += h0[k]     * g[k];
            a1 += h0[k + 1] * g[k + 1];
        }
        gA[n0 * ROWA + tid] = cst[tid] + a0 + a1;
    }
}

// ---------------------------------------------------------------------------
// K3: pair tables P[t][a][b][c] = dot(relu(is2*u[a] + 0.5*u[b] + b1), Gt[:,tc])
// Grid: 129 * 9 blocks, 256 threads. Gt staged in LDS (43KB); 2p x 3tc
// register tile per thread.
// ---------------------------------------------------------------------------
__global__ __launch_bounds__(256) void k_pair(const float* __restrict__ b1,
                                              float* __restrict__ ws, int rowP) {
    const float* u   = ws + U_OFF;
    const float* gGt = ws + GT_OFF;
    float* P         = ws + P_OFF;

    const int a  = blockIdx.x / NBT;
    const int b0 = (blockIdx.x % NBT) * BT;

    __shared__ float ua[D1];          // is2*u[a] + b1 folded
    __shared__ float hp[BT * D1];     // relu'd pair hidden, 8KB
    __shared__ float gt[D1 * 84];     // Gt staged, 43KB
    const int tid = threadIdx.x;

    if (tid < D1) ua[tid] = IS2 * u[a * D1 + tid] + b1[tid];
    // coalesced Gt stage: 10752 floats = 2688 float4
    {
        const float4* src = (const float4*)gGt;
        float4* dst = (float4*)gt;
        for (int i = tid; i < D1 * 84 / 4; i += 256) dst[i] = src[i];
    }
    __syncthreads();

    for (int e = tid; e < BT * D1; e += 256) {
        int p = e / D1, k = e % D1; int b = b0 + p;
        float val = 0.f;
        if (b < NE) val = fmaxf(ua[k] + 0.5f * u[b * D1 + k], 0.f);
        hp[e] = val;
    }
    __syncthreads();

    // 2p x 3tc tiles: 8 * 28 = 224 tiles; threads 224..255 idle.
    if (tid < (BT / 2) * 28) {
        const int p0  = (tid / 28) * 2;
        const int tc0 = (tid % 28) * 3;       // 3 | 21 -> tile within one t
        const float* hA = hp + p0 * D1;
        const float* hB = hA + D1;

        float e00 = 0.f, e01 = 0.f, e02 = 0.f, e10 = 0.f, e11 = 0.f, e12 = 0.f;
        float o00 = 0.f, o01 = 0.f, o02 = 0.f, o10 = 0.f, o11 = 0.f, o12 = 0.f;
#pragma unroll 4
        for (int k = 0; k < D1; k += 2) {
            float ha0 = hA[k], hb0 = hB[k];
            float ha1 = hA[k + 1], hb1 = hB[k + 1];
            const float* g0 = gt + k * 84 + tc0;
            const float* g1 = g0 + 84;
            float ge0 = g0[0], ge1 = g0[1], ge2 = g0[2];
            float go0 = g1[0], go1 = g1[1], go2 = g1[2];
            e00 += ha0 * ge0; e01 += ha0 * ge1; e02 += ha0 * ge2;
            e10 += hb0 * ge0; e11 += hb0 * ge1; e12 += hb0 * ge2;
            o00 += ha1 * go0; o01 += ha1 * go1; o02 += ha1 * go2;
            o10 += hb1 * go0; o11 += hb1 * go1; o12 += hb1 * go2;
        }

        const int t  = tc0 / DF;
        const int c0 = tc0 - t * DF;
        const long long rbase = (long long)(t * NE * NE + a * NE);
        const int bA = b0 + p0, bB = bA + 1;
        if (bA < NE) {
            float* dst = P + (rbase + bA) * rowP + c0;
            dst[0] = e00 + o00; dst[1] = e01 + o01; dst[2] = e02 + o02;
        }
        if (bB < NE) {
            float* dst = P + (rbase + bB) * rowP + c0;
            dst[0] = e10 + o10; dst[1] = e11 + o11; dst[2] = e12 + o12;
        }
    }
}

// ---------------------------------------------------------------------------
// K4: main pass, 6 threads per graph. Lane q in 0..4 reads float4 chunk q of
// all 5 gathered rows (A' + 4 P-rows) and writes out[c=4q..4q+3]; lane q=5
// reads scalar c=20. A given row's 128B line is consumed by its 6 lanes in
// the SAME load instruction -> each line fetched exactly once (~11 lines in
// flight per wave vs 40KB+ before; kills the L1-thrash 6x refetch).
// Summation order per element unchanged vs previous version.
// ---------------------------------------------------------------------------
__global__ __launch_bounds__(GPB * TPG) void k_main(const int* __restrict__ inst,
                                                    const float* __restrict__ ws,
                                                    float* __restrict__ out,
                                                    long long n_graphs, int rowP) {
    const float* gA = ws + A_OFF;
    const float* P  = ws + P_OFF;

    __shared__ int si[GPB * 5];             // 640B
    const int tid = threadIdx.x;
    const long long gbase = (long long)blockIdx.x * GPB;

    // coalesced index stage (160 consecutive ints)
    if (tid < GPB * 5) {
        long long lim = (n_graphs - gbase) * 5;
        si[tid] = (tid < lim) ? inst[gbase * 5 + tid] : 0;
    }
    __syncthreads();

    const int gl = tid / TPG;   // 0..31  graph within block
    const int q  = tid % TPG;   // 0..5   16B chunk
    const long long g = gbase + gl;
    if (g >= n_graphs) return;

    const int n0 = si[gl * 5 + 0];
    const int n1 = si[gl * 5 + 1];
    const int n2 = si[gl * 5 + 2];
    const int n3 = si[gl * 5 + 3];
    const int n4 = si[gl * 5 + 4];

    const int nn = NE * NE;
    const float* r0 = gA + n0 * ROWA;
    const float* r1 = P + (long long)(0 * nn + n0 * NE + n1) * rowP;
    const float* r2 = P + (long long)(1 * nn + n0 * NE + n2) * rowP;
    const float* r3 = P + (long long)(2 * nn + n0 * NE + n3) * rowP;
    const float* r4 = P + (long long)(3 * nn + n0 * NE + n4) * rowP;

    float* og = out + g * NC;
    if (q < 5) {
        const int o = q * 4;
        float4 a0 = *(const float4*)(r0 + o);
        float4 a1 = *(const float4*)(r1 + o);
        float4 a2 = *(const float4*)(r2 + o);
        float4 a3 = *(const float4*)(r3 + o);
        float4 a4 = *(const float4*)(r4 + o);
        og[o + 0] = a0.x + a1.x + a2.x + a3.x + a4.x;
        og[o + 1] = a0.y + a1.y + a2.y + a3.y + a4.y;
        og[o + 2] = a0.z + a1.z + a2.z + a3.z + a4.z;
        og[o + 3] = a0.w + a1.w + a2.w + a3.w + a4.w;
    } else {
        og[20] = r0[20] + r1[20] + r2[20] + r3[20] + r4[20];
    }
}

// ---------------------------------------------------------------------------
extern "C" void kernel_launch(void* const* d_in, const int* in_sizes, int n_in,
                              void* d_out, int out_size, void* d_ws, size_t ws_size,
                              hipStream_t stream) {
    const int*   inst = (const int*)d_in[0];    // [4,256,256,5]
    const int*   cn   = (const int*)d_in[1];    // [21,5]
    const float* emb  = (const float*)d_in[2];  // [129,21]
    const float* W1   = (const float*)d_in[3];  // [21,128]
    const float* b1   = (const float*)d_in[4];  // [128]
    const float* W2   = (const float*)d_in[5];  // [128,21]
    const float* b2   = (const float*)d_in[6];  // [21]
    float* out = (float*)d_out;
    float* ws  = (float*)d_ws;

    const long long n_graphs = (long long)in_sizes[0] / 5;   // 262144
    const int nblk_main = (int)((n_graphs + GPB - 1) / GPB); // 8192

    // one 128B-aligned cache line per pair-row if workspace permits (8.8MB)
    const int rowP =
        (ws_size >= (size_t)(P_OFF + P_ELEMS32) * sizeof(float)) ? 32 : 24;

    k_u      <<<dim3(NE),        dim3(D1),        0, stream>>>(emb, W1, ws + U_OFF);
    k_class_a<<<dim3(NC),        dim3(D1),        0, stream>>>(cn, b1, W2, b2, ws);
    k_class_b<<<dim3(53),        dim3(256),       0, stream>>>(W2, ws);
    k_class_c<<<dim3(NE),        dim3(D1),        0, stream>>>(b1, ws);
    k_pair   <<<dim3(NE * NBT),  dim3(256),       0, stream>>>(b1, ws, rowP);
    k_main   <<<dim3(nblk_main), dim3(GPB * TPG), 0, stream>>>(inst, ws, out, n_graphs, rowP);
}